// Round 1
// baseline (1882.251 us; speedup 1.0000x reference)
//
#include <hip/hip_runtime.h>

// ---------------- static problem dims ----------------
#define B_G   32
#define NXP   1024
#define NYP   512
#define NX_T  32768
#define NY_T  16384
#define E_T   65536
#define F_SZ  256
#define EMB_S 256
#define H_SZ  512
#define VOC   512

// d_out offsets (in floats), concatenated tuple:
// (y3, tgt_edge_index, tgt_edge_type, y_score, y_edge_rel_score, embeds_out, a1, a2, a3)
static const long O_Y3  = 0;
static const long O_EI  = 4194304;
static const long O_ET  = 4325376;
static const long O_YS  = 4390912;
static const long O_REL = 12779520;
static const long O_EMB = 13238272;
static const long O_A1  = 21626880;
static const long O_A2  = 38404096;
static const long O_A3  = 55181312;

using bf16x8 = __attribute__((ext_vector_type(8))) __bf16;
using f32x4  = __attribute__((ext_vector_type(4))) float;

__device__ __forceinline__ ushort f2bf(float f) {
  union { float f; unsigned u; } v; v.f = f;
  return (ushort)((v.u + 0x7FFFu + ((v.u >> 16) & 1u)) >> 16);
}
__device__ __forceinline__ float bf2f(ushort s) {
  union { unsigned u; float f; } v; v.u = ((unsigned)s) << 16;
  return v.f;
}

// ---------------- generic MFMA GEMM ----------------
// C[M,N] = epilogue( scale * A[M,K](bf16) @ Bt[N,K](bf16)^T )
// epilogue: (+addC)(+bias)(relu) -> outF (f32) and/or outB (bf16)
struct GemmP {
  const ushort* A; const ushort* Bt;
  float* outF; ushort* outB;
  const float* addC; const float* bias;
  long sA, sBt, sOutF, sOutB, sAddC;
  int lda, ldb, ldoF, ldoB, ldC;
  int M, N, K;
  float scale; int relu;
};

__global__ __launch_bounds__(256) void gemm_k(GemmP p) {
  __shared__ __align__(16) ushort As[128 * 32];
  __shared__ __align__(16) ushort Bs[128 * 32];
  const int tid  = threadIdx.x;
  const int wave = tid >> 6, lane = tid & 63;
  const int bm = blockIdx.x * 128, bn = blockIdx.y * 128;
  const int z  = blockIdx.z;
  const ushort* A  = p.A  + (long)z * p.sA;
  const ushort* Bt = p.Bt + (long)z * p.sBt;

  const int wm = (wave >> 1) * 64, wn = (wave & 1) * 64;
  const int lrow = lane & 15, lk = (lane >> 4) * 8;

  // staging: thread t covers 16B-chunks c=2t,2t+1; chunk c -> row c>>2, seg (c&3)*8
  const int c0 = 2 * tid, c1 = 2 * tid + 1;
  const int r0s = c0 >> 2, s0s = (c0 & 3) * 8;
  const int r1s = c1 >> 2, s1s = (c1 & 3) * 8;
  const ushort* pa0 = &A [(long)(bm + r0s) * p.lda + s0s];
  const ushort* pa1 = &A [(long)(bm + r1s) * p.lda + s1s];
  const ushort* pb0 = &Bt[(long)(bn + r0s) * p.ldb + s0s];
  const ushort* pb1 = &Bt[(long)(bn + r1s) * p.ldb + s1s];

  f32x4 acc[4][4];
#pragma unroll
  for (int m = 0; m < 4; ++m)
#pragma unroll
    for (int n = 0; n < 4; ++n) acc[m][n] = f32x4{0.f, 0.f, 0.f, 0.f};

  int4 ra0 = *(const int4*)pa0, ra1 = *(const int4*)pa1;
  int4 rb0 = *(const int4*)pb0, rb1 = *(const int4*)pb1;

  for (int k0 = 0; k0 < p.K; k0 += 32) {
    __syncthreads();
    *(int4*)&As[tid * 16]     = ra0;
    *(int4*)&As[tid * 16 + 8] = ra1;
    *(int4*)&Bs[tid * 16]     = rb0;
    *(int4*)&Bs[tid * 16 + 8] = rb1;
    __syncthreads();
    if (k0 + 32 < p.K) {   // prefetch next tile (overlaps MFMA)
      ra0 = *(const int4*)(pa0 + k0 + 32);
      ra1 = *(const int4*)(pa1 + k0 + 32);
      rb0 = *(const int4*)(pb0 + k0 + 32);
      rb1 = *(const int4*)(pb1 + k0 + 32);
    }
    bf16x8 af[4], bfr[4];
#pragma unroll
    for (int m = 0; m < 4; ++m)
      af[m] = *(const bf16x8*)&As[(wm + m * 16 + lrow) * 32 + lk];
#pragma unroll
    for (int n = 0; n < 4; ++n)
      bfr[n] = *(const bf16x8*)&Bs[(wn + n * 16 + lrow) * 32 + lk];
#pragma unroll
    for (int m = 0; m < 4; ++m)
#pragma unroll
      for (int n = 0; n < 4; ++n)
        acc[m][n] = __builtin_amdgcn_mfma_f32_16x16x32_bf16(af[m], bfr[n], acc[m][n], 0, 0, 0);
  }

  const int rr0 = (lane >> 4) * 4;   // C/D: col=lane&15, row=(lane>>4)*4+j
#pragma unroll
  for (int m = 0; m < 4; ++m) {
    const int row = bm + wm + m * 16 + rr0;
#pragma unroll
    for (int n = 0; n < 4; ++n) {
      const int col = bn + wn + n * 16 + lrow;
#pragma unroll
      for (int j = 0; j < 4; ++j) {
        float v = acc[m][n][j] * p.scale;
        const long r = row + j;
        if (p.addC) v += p.addC[(long)z * p.sAddC + r * p.ldC + col];
        if (p.bias) v += p.bias[col];
        if (p.relu) v = fmaxf(v, 0.f);
        if (p.outF) p.outF[(long)z * p.sOutF + r * p.ldoF + col] = v;
        if (p.outB) p.outB[(long)z * p.sOutB + r * p.ldoB + col] = f2bf(v);
      }
    }
  }
}

// ---------------- helper kernels ----------------
struct TD { const float* src; ushort* dst; int K; int N; };
struct TDs { TD d[19]; };
// dst[n*K+k] = bf16(src[k*N+n])
__global__ void transpose_k(TDs t) {
  TD d = t.d[blockIdx.y];
  int idx = blockIdx.x * 256 + threadIdx.x;
  int total = d.K * d.N;
  if (idx >= total) return;
  int n = idx / d.K, k = idx - n * d.K;
  d.dst[idx] = f2bf(d.src[(long)k * d.N + n]);
}

__global__ void cvt_k(const float* src, ushort* dst, long n4) {
  long i = (long)blockIdx.x * 256 + threadIdx.x;
  if (i >= n4) return;
  float4 v = *(const float4*)&src[i * 4];
  ushort4 o; o.x = f2bf(v.x); o.y = f2bf(v.y); o.z = f2bf(v.z); o.w = f2bf(v.w);
  *(ushort4*)&dst[i * 4] = o;
}

// per-graph transpose: xT[b][f][j] = x[b*1024+j][f]
__global__ __launch_bounds__(256) void xT_k(const float* x, ushort* xT) {
  __shared__ float t[32][33];
  int b = blockIdx.z;
  int j0 = blockIdx.x * 32, f0 = blockIdx.y * 32;
  int tx = threadIdx.x & 31, ty = threadIdx.x >> 5;
#pragma unroll
  for (int r = ty; r < 32; r += 8)
    t[r][tx] = x[((long)b * NXP + j0 + r) * F_SZ + f0 + tx];
  __syncthreads();
#pragma unroll
  for (int r = ty; r < 32; r += 8)
    xT[((long)b * F_SZ + f0 + r) * NXP + j0 + tx] = f2bf(t[tx][r]);
}

__global__ void gather_k(const float* emb, const int* tgt_y, ushort* y0b) {
  long i = (long)blockIdx.x * 256 + threadIdx.x;  // NY*64
  int n = (int)(i >> 6), c = (int)(i & 63) * 4;
  int row = tgt_y[n];
  float4 v = *(const float4*)&emb[(long)row * EMB_S + c];
  ushort4 o; o.x = f2bf(v.x); o.y = f2bf(v.y); o.z = f2bf(v.z); o.w = f2bf(v.w);
  *(ushort4*)&y0b[(long)n * EMB_S + c] = o;
}

__global__ __launch_bounds__(256) void softmax_k(const ushort* S, float* aF, ushort* aB) {
  __shared__ float red[8];
  const long row = blockIdx.x;
  const int tid = threadIdx.x, lane = tid & 63, wave = tid >> 6;
  const ushort* s = S + row * 1024;
  ushort4 u = *(const ushort4*)&s[tid * 4];
  float v0 = bf2f(u.x), v1 = bf2f(u.y), v2 = bf2f(u.z), v3 = bf2f(u.w);
  float m = fmaxf(fmaxf(v0, v1), fmaxf(v2, v3));
#pragma unroll
  for (int o = 32; o; o >>= 1) m = fmaxf(m, __shfl_xor(m, o, 64));
  if (lane == 0) red[wave] = m;
  __syncthreads();
  m = fmaxf(fmaxf(red[0], red[1]), fmaxf(red[2], red[3]));
  float e0 = __expf(v0 - m), e1 = __expf(v1 - m), e2 = __expf(v2 - m), e3 = __expf(v3 - m);
  float sm = e0 + e1 + e2 + e3;
#pragma unroll
  for (int o = 32; o; o >>= 1) sm += __shfl_xor(sm, o, 64);
  if (lane == 0) red[4 + wave] = sm;
  __syncthreads();
  float inv = 1.0f / (red[4] + red[5] + red[6] + red[7]);
  float4 a; a.x = e0 * inv; a.y = e1 * inv; a.z = e2 * inv; a.w = e3 * inv;
  *(float4*)&aF[row * 1024 + tid * 4] = a;
  ushort4 ob; ob.x = f2bf(a.x); ob.y = f2bf(a.y); ob.z = f2bf(a.z); ob.w = f2bf(a.w);
  *(ushort4*)&aB[row * 1024 + tid * 4] = ob;
}

// agg[dst] += P[src] for edges of type t
__global__ void scatter_k(const ushort* P, const int* ei, const int* et,
                          float* agg, int no, int t) {
  long idx = (long)blockIdx.x * 256 + threadIdx.x;
  int per = no >> 2;
  int e = (int)(idx / per);
  int c = (int)(idx - (long)e * per) * 4;
  if (et[e] != t) return;
  int srcn = ei[e], dstn = ei[E_T + e];
  ushort4 u = *(const ushort4*)&P[(long)srcn * no + c];
  float* ag = &agg[(long)dstn * no + c];
  atomicAdd(&ag[0], bf2f(u.x));
  atomicAdd(&ag[1], bf2f(u.y));
  atomicAdd(&ag[2], bf2f(u.z));
  atomicAdd(&ag[3], bf2f(u.w));
}

// G1[n] = y3[n] @ Wg[0:256,:], G2[n] = y3[n] @ Wg[256:512,:]
__global__ void gsd_k(const ushort* y3b, const float* Wg, float* G1, float* G2) {
  int n = blockIdx.x * 256 + threadIdx.x;
  float a[7] = {0, 0, 0, 0, 0, 0, 0}, b[7] = {0, 0, 0, 0, 0, 0, 0};
  const ushort* yr = &y3b[(long)n * EMB_S];
  for (int k = 0; k < 256; ++k) {
    float yv = bf2f(yr[k]);
    const float* w1 = &Wg[(long)k * 7];
    const float* w2 = &Wg[(long)(k + 256) * 7];
#pragma unroll
    for (int r = 0; r < 7; ++r) { a[r] += yv * w1[r]; b[r] += yv * w2[r]; }
  }
#pragma unroll
  for (int r = 0; r < 7; ++r) { G1[(long)n * 7 + r] = a[r]; G2[(long)n * 7 + r] = b[r]; }
}

__global__ void erel_k(const float* G1, const float* G2, const int* ei,
                       const float* bg, float* outR) {
  long idx = (long)blockIdx.x * 256 + threadIdx.x;
  int e = (int)(idx / 7), r = (int)(idx - (long)e * 7);
  outR[idx] = G1[(long)ei[e] * 7 + r] + G2[(long)ei[E_T + e] * 7 + r] + bg[r];
}

__global__ void icopy_k(const int* ei, const int* et, float* oEI, float* oET) {
  int idx = blockIdx.x * 256 + threadIdx.x;
  if (idx < 2 * E_T) oEI[idx] = (float)ei[idx];
  else oET[idx - 2 * E_T] = (float)et[idx - 2 * E_T];
}

// ---------------- host side ----------------
static void gemm(hipStream_t st,
                 const ushort* A, long sA, int lda,
                 const ushort* Bt, long sBt, int ldb,
                 int M, int N, int K, int Z,
                 float* outF, long sOF, int ldoF,
                 ushort* outB, long sOB, int ldoB,
                 const float* addC, long sC, int ldC,
                 const float* bias, float scale, int relu) {
  GemmP p;
  p.A = A; p.Bt = Bt; p.outF = outF; p.outB = outB; p.addC = addC; p.bias = bias;
  p.sA = sA; p.sBt = sBt; p.sOutF = sOF; p.sOutB = sOB; p.sAddC = sC;
  p.lda = lda; p.ldb = ldb; p.ldoF = ldoF; p.ldoB = ldoB; p.ldC = ldC;
  p.M = M; p.N = N; p.K = K; p.scale = scale; p.relu = relu;
  dim3 grid(M / 128, N / 128, Z);
  hipLaunchKernelGGL(gemm_k, grid, dim3(256), 0, st, p);
}

extern "C" void kernel_launch(void* const* d_in, const int* in_sizes, int n_in,
                              void* d_out_, int out_size, void* d_ws, size_t ws_size,
                              hipStream_t stream) {
  const float* x     = (const float*)d_in[0];
  const int*   tgt_y = (const int*)d_in[1];
  const int*   ei    = (const int*)d_in[2];
  const int*   et    = (const int*)d_in[3];
  const float* emb   = (const float*)d_in[6];
  const float* Wz    = (const float*)d_in[7];
  const float* bz    = (const float*)d_in[8];
  const float* Wg    = (const float*)d_in[9];
  const float* bg    = (const float*)d_in[10];
  const float* We[3] = {(const float*)d_in[11], (const float*)d_in[15], (const float*)d_in[19]};
  const float* Wq[3] = {(const float*)d_in[12], (const float*)d_in[16], (const float*)d_in[20]};
  const float* Wc[3] = {(const float*)d_in[13], (const float*)d_in[17], (const float*)d_in[21]};
  const float* bb[3] = {(const float*)d_in[14], (const float*)d_in[18], (const float*)d_in[22]};
  float* out = (float*)d_out_;

  // ---- workspace layout (ushort units) ----
  ushort* wsu   = (ushort*)d_ws;
  ushort* WzT   = wsu + 0;         // 131072
  ushort* We1T  = wsu + 131072;    // 4*131072
  ushort* We2T  = wsu + 655360;    // 4*262144
  ushort* We3T  = wsu + 1703936;   // 4*131072
  ushort* Wq1T  = wsu + 2228224;   // 65536
  ushort* Wq2T  = wsu + 2293760;   // 131072
  ushort* Wq3T  = wsu + 2424832;   // 131072
  ushort* Wc1T  = wsu + 2555904;   // 131072
  ushort* Wc2T  = wsu + 2686976;   // 131072
  ushort* Wc3T  = wsu + 2818048;   // 65536
  ushort* xb    = wsu + 2883584;   // 8388608   bf16 x [32768,256]
  ushort* xTb   = wsu + 11272192;  // 8388608   bf16 x^T per graph [32][256][1024]
  ushort* alphab= wsu + 19660800;  // 16777216  bf16 alpha
  ushort* qctx  = wsu + 36438016;  // 4194304   bf16 q / ctx [16384,256]
  ushort* ybuf  = wsu + 40632320;  // 8388608   bf16 y0/y1/y2/y3
  float*  G1    = (float*)(wsu + 49020928);   // 114688 floats
  float*  G2    = G1 + 114688;                // 114688 floats

  // ---- weight transposes (fp32 [K,N] -> bf16 [N,K]) ----
  TDs td; int di = 0;
  td.d[di++] = {Wz, WzT, 256, 512};
  for (int t = 0; t < 4; ++t) td.d[di++] = {We[0] + (long)t * 131072, We1T + (long)t * 131072, 256, 512};
  for (int t = 0; t < 4; ++t) td.d[di++] = {We[1] + (long)t * 262144, We2T + (long)t * 262144, 512, 512};
  for (int t = 0; t < 4; ++t) td.d[di++] = {We[2] + (long)t * 131072, We3T + (long)t * 131072, 512, 256};
  td.d[di++] = {Wq[0], Wq1T, 256, 256};
  td.d[di++] = {Wq[1], Wq2T, 512, 256};
  td.d[di++] = {Wq[2], Wq3T, 512, 256};
  td.d[di++] = {Wc[0], Wc1T, 256, 512};
  td.d[di++] = {Wc[1], Wc2T, 256, 512};
  td.d[di++] = {Wc[2], Wc3T, 256, 256};
  hipLaunchKernelGGL(transpose_k, dim3(1024, 19), dim3(256), 0, stream, td);

  hipLaunchKernelGGL(cvt_k, dim3(8192), dim3(256), 0, stream, x, xb, (long)2097152);
  hipLaunchKernelGGL(xT_k, dim3(32, 8, 32), dim3(256), 0, stream, x, xTb);
  hipLaunchKernelGGL(gather_k, dim3(4096), dim3(256), 0, stream, emb, tgt_y, ybuf);

  // embeds_out = y0 @ Wz + bz
  gemm(stream, ybuf, 0, 256, WzT, 0, 256, NY_T, 512, 256, 1,
       out + O_EMB, 0, 512, nullptr, 0, 0, nullptr, 0, 0, bz, 1.0f, 0);

  const ushort* WeT_l[3] = {We1T, We2T, We3T};
  const ushort* WqT_l[3] = {Wq1T, Wq2T, Wq3T};
  const ushort* WcT_l[3] = {Wc1T, Wc2T, Wc3T};
  const int ni_l[3] = {256, 512, 512}, no_l[3] = {512, 512, 256};
  float* aggs[3]    = {out + O_A2 + 8388608, out + O_A3 + 8388608, out + O_Y3};
  ushort* scoresS[3]= {(ushort*)(out + O_A2), (ushort*)(out + O_A3), (ushort*)(out + O_YS)};
  ushort* Pslot[3]  = {(ushort*)(out + O_A3), (ushort*)(out + O_A3), (ushort*)(out + O_YS)};
  float* alphaO[3]  = {out + O_A1, out + O_A2, out + O_A3};

  for (int l = 0; l < 3; ++l) {
    const int ni = ni_l[l], no = no_l[l];
    float* agg = aggs[l];
    hipMemsetAsync(agg, 0, (size_t)NY_T * no * 4, stream);
    // edge-type message GEMMs + scatter into agg
    for (int t = 0; t < 4; ++t) {
      gemm(stream, ybuf, 0, ni, WeT_l[l] + (long)t * no * ni, 0, ni,
           NY_T, no, ni, 1, nullptr, 0, 0, Pslot[l], 0, no,
           nullptr, 0, 0, nullptr, 1.0f, 0);
      long nthr = (long)E_T * (no / 4);
      hipLaunchKernelGGL(scatter_k, dim3((unsigned)(nthr / 256)), dim3(256), 0, stream,
                         Pslot[l], ei, et, agg, no, t);
    }
    // q = y @ Wq
    gemm(stream, ybuf, 0, ni, WqT_l[l], 0, ni, NY_T, 256, ni, 1,
         nullptr, 0, 0, qctx, 0, 256, nullptr, 0, 0, nullptr, 1.0f, 0);
    // scores = q @ x^T / 16  (batched over 32 graphs), bf16
    gemm(stream, qctx, (long)512 * 256, 256, xb, (long)1024 * 256, 256,
         512, 1024, 256, 32, nullptr, 0, 0, scoresS[l], (long)512 * 1024, 1024,
         nullptr, 0, 0, nullptr, 0.0625f, 0);
    // softmax -> alpha (f32 to output, bf16 to ws)
    hipLaunchKernelGGL(softmax_k, dim3(16384), dim3(256), 0, stream,
                       scoresS[l], alphaO[l], alphab);
    // ctx = alpha @ x  (batched), bf16
    gemm(stream, alphab, (long)512 * 1024, 1024, xTb, (long)256 * 1024, 1024,
         512, 256, 1024, 32, nullptr, 0, 0, qctx, (long)512 * 256, 256,
         nullptr, 0, 0, nullptr, 1.0f, 0);
    // y_next = relu(agg + ctx @ Wc + b)
    gemm(stream, qctx, 0, 256, WcT_l[l], 0, 256, NY_T, no, 256, 1,
         (l == 2) ? out + O_Y3 : nullptr, 0, no, ybuf, 0, no,
         agg, 0, no, bb[l], 1.0f, 1);
  }

  // y_score = y3 @ Wz + bz
  gemm(stream, ybuf, 0, 256, WzT, 0, 256, NY_T, 512, 256, 1,
       out + O_YS, 0, 512, nullptr, 0, 0, nullptr, 0, 0, bz, 1.0f, 0);
  // edge-rel scores
  hipLaunchKernelGGL(gsd_k, dim3(64), dim3(256), 0, stream, ybuf, Wg, G1, G2);
  hipLaunchKernelGGL(erel_k, dim3(1792), dim3(256), 0, stream, G1, G2, ei, bg, out + O_REL);
  hipLaunchKernelGGL(icopy_k, dim3(768), dim3(256), 0, stream, ei, et, out + O_EI, out + O_ET);
}

// Round 2
// 796.325 us; speedup vs baseline: 2.3637x; 2.3637x over previous
//
#include <hip/hip_runtime.h>

// ---------------- static problem dims ----------------
#define B_G   32
#define NXP   1024
#define NYP   512
#define NX_T  32768
#define NY_T  16384
#define E_T   65536
#define F_SZ  256
#define EMB_S 256
#define H_SZ  512
#define VOC   512

// d_out offsets (in floats), concatenated tuple:
// (y3, tgt_edge_index, tgt_edge_type, y_score, y_edge_rel_score, embeds_out, a1, a2, a3)
static const long O_Y3  = 0;
static const long O_EI  = 4194304;
static const long O_ET  = 4325376;
static const long O_YS  = 4390912;
static const long O_REL = 12779520;
static const long O_EMB = 13238272;
static const long O_A1  = 21626880;
static const long O_A2  = 38404096;
static const long O_A3  = 55181312;

using bf16x8 = __attribute__((ext_vector_type(8))) __bf16;
using f32x4  = __attribute__((ext_vector_type(4))) float;

__device__ __forceinline__ ushort f2bf(float f) {
  union { float f; unsigned u; } v; v.f = f;
  return (ushort)((v.u + 0x7FFFu + ((v.u >> 16) & 1u)) >> 16);
}
__device__ __forceinline__ float bf2f(ushort s) {
  union { unsigned u; float f; } v; v.u = ((unsigned)s) << 16;
  return v.f;
}

__device__ __forceinline__ void g2l16(const ushort* g, ushort* l) {
  __builtin_amdgcn_global_load_lds(
      (const __attribute__((address_space(1))) void*)g,
      (__attribute__((address_space(3))) void*)l, 16, 0, 0);
}

// ---------------- generic MFMA GEMM (m97 structure: global_load_lds staging) ----
// C[M,N] = epilogue( scale * A[M,K](bf16) @ Bt[N,K](bf16)^T )
struct GemmP {
  const ushort* A; const ushort* Bt;
  float* outF; ushort* outB;
  const float* addC; const float* bias;
  long sA, sBt, sOutF, sOutB, sAddC;
  int lda, ldb, ldoF, ldoB, ldC;
  int M, N, K;
  float scale; int relu;
};

__global__ __launch_bounds__(256) void gemm_k(GemmP p) {
  __shared__ __align__(16) ushort As[128 * 32];
  __shared__ __align__(16) ushort Bs[128 * 32];
  const int tid  = threadIdx.x;
  const int wave = tid >> 6, lane = tid & 63;
  const int bm = blockIdx.x * 128, bn = blockIdx.y * 128;
  const int z  = blockIdx.z;
  const ushort* A  = p.A  + (long)z * p.sA;
  const ushort* Bt = p.Bt + (long)z * p.sBt;

  const int wm = (wave >> 1) * 64, wn = (wave & 1) * 64;
  const int lrow = lane & 15, lk = (lane >> 4) * 8;

  // staging: 16B chunk c covers row c>>2, seg (c&3)*8; LDS byte offset c*16
  // chunk c0=tid, c1=tid+256 -> LDS dest = wave-uniform base + lane*16 (required layout)
  const int c0 = tid, c1 = tid + 256;
  const ushort* pa0 = &A [(long)(bm + (c0 >> 2)) * p.lda + (c0 & 3) * 8];
  const ushort* pa1 = &A [(long)(bm + (c1 >> 2)) * p.lda + (c1 & 3) * 8];
  const ushort* pb0 = &Bt[(long)(bn + (c0 >> 2)) * p.ldb + (c0 & 3) * 8];
  const ushort* pb1 = &Bt[(long)(bn + (c1 >> 2)) * p.ldb + (c1 & 3) * 8];
  ushort* la0 = &As[c0 * 8];
  ushort* la1 = &As[c1 * 8];
  ushort* lb0 = &Bs[c0 * 8];
  ushort* lb1 = &Bs[c1 * 8];

  f32x4 acc[4][4];
#pragma unroll
  for (int m = 0; m < 4; ++m)
#pragma unroll
    for (int n = 0; n < 4; ++n) acc[m][n] = f32x4{0.f, 0.f, 0.f, 0.f};

  for (int k0 = 0; k0 < p.K; k0 += 32) {
    g2l16(pa0 + k0, la0);
    g2l16(pa1 + k0, la1);
    g2l16(pb0 + k0, lb0);
    g2l16(pb1 + k0, lb1);
    __syncthreads();   // drains vmcnt -> LDS tile ready
    bf16x8 af[4], bfr[4];
#pragma unroll
    for (int m = 0; m < 4; ++m)
      af[m] = *(const bf16x8*)&As[(wm + m * 16 + lrow) * 32 + lk];
#pragma unroll
    for (int n = 0; n < 4; ++n)
      bfr[n] = *(const bf16x8*)&Bs[(wn + n * 16 + lrow) * 32 + lk];
#pragma unroll
    for (int m = 0; m < 4; ++m)
#pragma unroll
      for (int n = 0; n < 4; ++n)
        acc[m][n] = __builtin_amdgcn_mfma_f32_16x16x32_bf16(af[m], bfr[n], acc[m][n], 0, 0, 0);
    __syncthreads();   // before overwriting LDS next iter
  }

  const int rr0 = (lane >> 4) * 4;   // C/D: col=lane&15, row=(lane>>4)*4+j
#pragma unroll
  for (int m = 0; m < 4; ++m) {
    const int row = bm + wm + m * 16 + rr0;
#pragma unroll
    for (int n = 0; n < 4; ++n) {
      const int col = bn + wn + n * 16 + lrow;
#pragma unroll
      for (int j = 0; j < 4; ++j) {
        float v = acc[m][n][j] * p.scale;
        const long r = row + j;
        if (p.addC) v += p.addC[(long)z * p.sAddC + r * p.ldC + col];
        if (p.bias) v += p.bias[col];
        if (p.relu) v = fmaxf(v, 0.f);
        if (p.outF) p.outF[(long)z * p.sOutF + r * p.ldoF + col] = v;
        if (p.outB) p.outB[(long)z * p.sOutB + r * p.ldoB + col] = f2bf(v);
      }
    }
  }
}

// ---------------- helper kernels ----------------
struct TD { const float* src; ushort* dst; int K; int N; };
struct TDs { TD d[19]; };
// dst[n*K+k] = bf16(src[k*N+n])
__global__ void transpose_k(TDs t) {
  TD d = t.d[blockIdx.y];
  int idx = blockIdx.x * 256 + threadIdx.x;
  int total = d.K * d.N;
  if (idx >= total) return;
  int n = idx / d.K, k = idx - n * d.K;
  d.dst[idx] = f2bf(d.src[(long)k * d.N + n]);
}

__global__ void cvt_k(const float* src, ushort* dst, long n4) {
  long i = (long)blockIdx.x * 256 + threadIdx.x;
  if (i >= n4) return;
  float4 v = *(const float4*)&src[i * 4];
  ushort4 o; o.x = f2bf(v.x); o.y = f2bf(v.y); o.z = f2bf(v.z); o.w = f2bf(v.w);
  *(ushort4*)&dst[i * 4] = o;
}

// per-graph transpose: xT[b][f][j] = x[b*1024+j][f]
__global__ __launch_bounds__(256) void xT_k(const float* x, ushort* xT) {
  __shared__ float t[32][33];
  int b = blockIdx.z;
  int j0 = blockIdx.x * 32, f0 = blockIdx.y * 32;
  int tx = threadIdx.x & 31, ty = threadIdx.x >> 5;
#pragma unroll
  for (int r = ty; r < 32; r += 8)
    t[r][tx] = x[((long)b * NXP + j0 + r) * F_SZ + f0 + tx];
  __syncthreads();
#pragma unroll
  for (int r = ty; r < 32; r += 8)
    xT[((long)b * F_SZ + f0 + r) * NXP + j0 + tx] = f2bf(t[tx][r]);
}

__global__ void gather_k(const float* emb, const int* tgt_y, ushort* y0b) {
  long i = (long)blockIdx.x * 256 + threadIdx.x;  // NY*64
  int n = (int)(i >> 6), c = (int)(i & 63) * 4;
  int row = tgt_y[n];
  float4 v = *(const float4*)&emb[(long)row * EMB_S + c];
  ushort4 o; o.x = f2bf(v.x); o.y = f2bf(v.y); o.z = f2bf(v.z); o.w = f2bf(v.w);
  *(ushort4*)&y0b[(long)n * EMB_S + c] = o;
}

// softmax over rows of 1024; reads bf16 scores, writes f32 alpha (out) + bf16 in-place
__global__ __launch_bounds__(256) void softmax_k(ushort* S, float* aF) {
  __shared__ float red[8];
  const long row = blockIdx.x;
  const int tid = threadIdx.x, lane = tid & 63, wave = tid >> 6;
  ushort* s = S + row * 1024;
  ushort4 u = *(const ushort4*)&s[tid * 4];
  float v0 = bf2f(u.x), v1 = bf2f(u.y), v2 = bf2f(u.z), v3 = bf2f(u.w);
  float m = fmaxf(fmaxf(v0, v1), fmaxf(v2, v3));
#pragma unroll
  for (int o = 32; o; o >>= 1) m = fmaxf(m, __shfl_xor(m, o, 64));
  if (lane == 0) red[wave] = m;
  __syncthreads();
  m = fmaxf(fmaxf(red[0], red[1]), fmaxf(red[2], red[3]));
  float e0 = __expf(v0 - m), e1 = __expf(v1 - m), e2 = __expf(v2 - m), e3 = __expf(v3 - m);
  float sm = e0 + e1 + e2 + e3;
#pragma unroll
  for (int o = 32; o; o >>= 1) sm += __shfl_xor(sm, o, 64);
  if (lane == 0) red[4 + wave] = sm;
  __syncthreads();
  float inv = 1.0f / (red[4] + red[5] + red[6] + red[7]);
  float4 a; a.x = e0 * inv; a.y = e1 * inv; a.z = e2 * inv; a.w = e3 * inv;
  *(float4*)&aF[row * 1024 + tid * 4] = a;
  ushort4 ob; ob.x = f2bf(a.x); ob.y = f2bf(a.y); ob.z = f2bf(a.z); ob.w = f2bf(a.w);
  *(ushort4*)&s[tid * 4] = ob;
}

// ---------------- CSR build (edges constant across layers) ----------------
__global__ void deg_k(const int* ei, int* cnt) {
  int e = blockIdx.x * 256 + threadIdx.x;
  atomicAdd(&cnt[ei[E_T + e]], 1);
}

__global__ __launch_bounds__(256) void scan_k(const int* cnt, int* ofs, int* cur) {
  __shared__ int sh[256];
  const int t = threadIdx.x;
  int s = 0;
  for (int i = 0; i < 64; ++i) s += cnt[t * 64 + i];
  sh[t] = s; __syncthreads();
  for (int d = 1; d < 256; d <<= 1) {
    int v = (t >= d) ? sh[t - d] : 0;
    __syncthreads();
    sh[t] += v;
    __syncthreads();
  }
  int run = sh[t] - s;   // exclusive prefix
  for (int i = 0; i < 64; ++i) {
    int v = cnt[t * 64 + i];
    ofs[t * 64 + i] = run; cur[t * 64 + i] = run;
    run += v;
  }
  if (t == 255) ofs[16384] = run;
}

__global__ void fill_k(const int* ei, const int* et, int* cur, ushort* adj) {
  int e = blockIdx.x * 256 + threadIdx.x;
  int d = ei[E_T + e];
  int pos = atomicAdd(&cur[d], 1);
  adj[pos] = (ushort)(ei[e] | (et[e] << 14));   // src(14b) | type(2b)
}

// agg[r][c..c+3] = sum over CSR edges of P[src][t*no + c..]
__global__ __launch_bounds__(256) void gather_agg_k(const ushort* P, const ushort* adj,
                                                    const int* ofs, float* agg,
                                                    int no, int ldP) {
  const int tpr = no >> 2;                         // threads per row
  const int r = blockIdx.x * (256 / tpr) + threadIdx.x / tpr;
  const int c = (threadIdx.x % tpr) * 4;
  const int s0 = ofs[r], s1 = ofs[r + 1];
  float4 acc = make_float4(0.f, 0.f, 0.f, 0.f);
  for (int i = s0; i < s1; ++i) {
    const unsigned a = adj[i];
    const int src = a & 0x3FFF;
    const int t = a >> 14;
    ushort4 u = *(const ushort4*)&P[(long)src * ldP + t * no + c];
    acc.x += bf2f(u.x); acc.y += bf2f(u.y); acc.z += bf2f(u.z); acc.w += bf2f(u.w);
  }
  *(float4*)&agg[(long)r * no + c] = acc;
}

// G1[n] = y3[n] @ Wg[0:256,:], G2[n] = y3[n] @ Wg[256:512,:]
__global__ void gsd_k(const ushort* y3b, const float* Wg, float* G1, float* G2) {
  int n = blockIdx.x * 256 + threadIdx.x;
  float a[7] = {0, 0, 0, 0, 0, 0, 0}, b[7] = {0, 0, 0, 0, 0, 0, 0};
  const ushort* yr = &y3b[(long)n * EMB_S];
  for (int k = 0; k < 256; ++k) {
    float yv = bf2f(yr[k]);
    const float* w1 = &Wg[(long)k * 7];
    const float* w2 = &Wg[(long)(k + 256) * 7];
#pragma unroll
    for (int r = 0; r < 7; ++r) { a[r] += yv * w1[r]; b[r] += yv * w2[r]; }
  }
#pragma unroll
  for (int r = 0; r < 7; ++r) { G1[(long)n * 7 + r] = a[r]; G2[(long)n * 7 + r] = b[r]; }
}

__global__ void erel_k(const float* G1, const float* G2, const int* ei,
                       const float* bg, float* outR) {
  long idx = (long)blockIdx.x * 256 + threadIdx.x;
  int e = (int)(idx / 7), r = (int)(idx - (long)e * 7);
  outR[idx] = G1[(long)ei[e] * 7 + r] + G2[(long)ei[E_T + e] * 7 + r] + bg[r];
}

__global__ void icopy_k(const int* ei, const int* et, float* oEI, float* oET) {
  int idx = blockIdx.x * 256 + threadIdx.x;
  if (idx < 2 * E_T) oEI[idx] = (float)ei[idx];
  else oET[idx - 2 * E_T] = (float)et[idx - 2 * E_T];
}

// ---------------- host side ----------------
static void gemm(hipStream_t st,
                 const ushort* A, long sA, int lda,
                 const ushort* Bt, long sBt, int ldb,
                 int M, int N, int K, int Z,
                 float* outF, long sOF, int ldoF,
                 ushort* outB, long sOB, int ldoB,
                 const float* addC, long sC, int ldC,
                 const float* bias, float scale, int relu) {
  GemmP p;
  p.A = A; p.Bt = Bt; p.outF = outF; p.outB = outB; p.addC = addC; p.bias = bias;
  p.sA = sA; p.sBt = sBt; p.sOutF = sOF; p.sOutB = sOB; p.sAddC = sC;
  p.lda = lda; p.ldb = ldb; p.ldoF = ldoF; p.ldoB = ldoB; p.ldC = ldC;
  p.M = M; p.N = N; p.K = K; p.scale = scale; p.relu = relu;
  dim3 grid(M / 128, N / 128, Z);
  hipLaunchKernelGGL(gemm_k, grid, dim3(256), 0, st, p);
}

extern "C" void kernel_launch(void* const* d_in, const int* in_sizes, int n_in,
                              void* d_out_, int out_size, void* d_ws, size_t ws_size,
                              hipStream_t stream) {
  const float* x     = (const float*)d_in[0];
  const int*   tgt_y = (const int*)d_in[1];
  const int*   ei    = (const int*)d_in[2];
  const int*   et    = (const int*)d_in[3];
  const float* emb   = (const float*)d_in[6];
  const float* Wz    = (const float*)d_in[7];
  const float* bz    = (const float*)d_in[8];
  const float* Wg    = (const float*)d_in[9];
  const float* bg    = (const float*)d_in[10];
  const float* We[3] = {(const float*)d_in[11], (const float*)d_in[15], (const float*)d_in[19]};
  const float* Wq[3] = {(const float*)d_in[12], (const float*)d_in[16], (const float*)d_in[20]};
  const float* Wc[3] = {(const float*)d_in[13], (const float*)d_in[17], (const float*)d_in[21]};
  const float* bb[3] = {(const float*)d_in[14], (const float*)d_in[18], (const float*)d_in[22]};
  float* out = (float*)d_out_;

  // ---- workspace layout (ushort units) ----
  ushort* wsu    = (ushort*)d_ws;
  ushort* WzT    = wsu + 0;          // 512x256            = 131072
  ushort* WETQ0  = wsu + 131072;     // 2304x256           = 589824
  ushort* WETQ1  = wsu + 720896;     // 2304x512           = 1179648
  ushort* WETQ2  = wsu + 1900544;    // 1280x512           = 655360
  ushort* Wc1T   = wsu + 2555904;    // 512x256            = 131072
  ushort* Wc2T   = wsu + 2686976;    // 512x256            = 131072
  ushort* Wc3T   = wsu + 2818048;    // 256x256            = 65536
  ushort* xb     = wsu + 2883584;    // bf16 x [32768,256] = 8388608
  ushort* xTb    = wsu + 11272192;   // bf16 xT [32][256][1024] = 8388608
  ushort* scoreb = wsu + 19660800;   // bf16 scores/alpha [16384,1024] = 16777216
  ushort* Pbuf   = wsu + 36438016;   // bf16 P [16384,2304] = 37748736 (also ctx [16384,256])
  ushort* ybuf   = wsu + 74186752;   // bf16 y [16384,512] = 8388608
  float*  agg    = (float*)(wsu + 82575360);  // f32 [16384,512] = 8388608 floats
  float*  G1     = (float*)(wsu + 99352576);  // 114688 floats
  float*  G2     = (float*)(wsu + 99581952);  // 114688 floats
  int*    cnt    = (int*)(wsu + 99811328);    // 16384
  int*    ofs    = (int*)(wsu + 99844096);    // 16385
  int*    cur    = (int*)(wsu + 99876992);    // 16384
  ushort* adj    = wsu + 99909760;            // 65536

  // ---- weight transposes: fused [4*no+256][ni] per layer + WzT + WcT ----
  ushort* WETQ[3] = {WETQ0, WETQ1, WETQ2};
  const int ni_l[3] = {256, 512, 512}, no_l[3] = {512, 512, 256};
  TDs td; int di = 0;
  td.d[di++] = {Wz, WzT, 256, 512};
  for (int l = 0; l < 3; ++l) {
    const int ni = ni_l[l], no = no_l[l];
    for (int t = 0; t < 4; ++t)
      td.d[di++] = {We[l] + (long)t * ni * no, WETQ[l] + (long)t * no * ni, ni, no};
    td.d[di++] = {Wq[l], WETQ[l] + (long)4 * no * ni, ni, 256};
  }
  td.d[di++] = {Wc[0], Wc1T, 256, 512};
  td.d[di++] = {Wc[1], Wc2T, 256, 512};
  td.d[di++] = {Wc[2], Wc3T, 256, 256};
  hipLaunchKernelGGL(transpose_k, dim3(1024, 19), dim3(256), 0, stream, td);

  hipLaunchKernelGGL(cvt_k, dim3(8192), dim3(256), 0, stream, x, xb, (long)2097152);
  hipLaunchKernelGGL(xT_k, dim3(32, 8, 32), dim3(256), 0, stream, x, xTb);
  hipLaunchKernelGGL(gather_k, dim3(4096), dim3(256), 0, stream, emb, tgt_y, ybuf);

  // ---- CSR build (once; edges shared by all layers) ----
  hipMemsetAsync(cnt, 0, 16384 * sizeof(int), stream);
  hipLaunchKernelGGL(deg_k, dim3(256), dim3(256), 0, stream, ei, cnt);
  hipLaunchKernelGGL(scan_k, dim3(1), dim3(256), 0, stream, cnt, ofs, cur);
  hipLaunchKernelGGL(fill_k, dim3(256), dim3(256), 0, stream, ei, et, cur, adj);

  // embeds_out = y0 @ Wz + bz
  gemm(stream, ybuf, 0, 256, WzT, 0, 256, NY_T, 512, 256, 1,
       out + O_EMB, 0, 512, nullptr, 0, 0, nullptr, 0, 0, bz, 1.0f, 0);

  const ushort* WcT_l[3] = {Wc1T, Wc2T, Wc3T};
  float* alphaO[3] = {out + O_A1, out + O_A2, out + O_A3};

  for (int l = 0; l < 3; ++l) {
    const int ni = ni_l[l], no = no_l[l];
    const int ldP = 4 * no + 256, qoff = 4 * no;
    // fused edge-type + Wq GEMM: P[NY, 4*no+256] bf16
    gemm(stream, ybuf, 0, ni, WETQ[l], 0, ni,
         NY_T, ldP, ni, 1, nullptr, 0, 0, Pbuf, 0, ldP,
         nullptr, 0, 0, nullptr, 1.0f, 0);
    // agg = CSR gather-sum of per-type messages
    hipLaunchKernelGGL(gather_agg_k, dim3(NY_T / (256 / (no >> 2))), dim3(256), 0, stream,
                       Pbuf, adj, ofs, agg, no, ldP);
    // scores = q @ x^T / 16 (batched over graphs), bf16 into scoreb
    gemm(stream, Pbuf + qoff, (long)512 * ldP, ldP, xb, (long)1024 * 256, 256,
         512, 1024, 256, 32, nullptr, 0, 0, scoreb, (long)512 * 1024, 1024,
         nullptr, 0, 0, nullptr, 0.0625f, 0);
    // softmax -> f32 alpha to output, bf16 alpha in-place
    hipLaunchKernelGGL(softmax_k, dim3(16384), dim3(256), 0, stream, scoreb, alphaO[l]);
    // ctx = alpha @ x (batched) -> front of Pbuf as [16384,256] bf16
    gemm(stream, scoreb, (long)512 * 1024, 1024, xTb, (long)256 * 1024, 1024,
         512, 256, 1024, 32, nullptr, 0, 0, Pbuf, (long)512 * 256, 256,
         nullptr, 0, 0, nullptr, 1.0f, 0);
    // y_next = relu(agg + ctx @ Wc + b)
    gemm(stream, Pbuf, 0, 256, WcT_l[l], 0, 256, NY_T, no, 256, 1,
         (l == 2) ? out + O_Y3 : nullptr, 0, no, ybuf, 0, no,
         agg, 0, no, bb[l], 1.0f, 1);
  }

  // y_score = y3 @ Wz + bz
  gemm(stream, ybuf, 0, 256, WzT, 0, 256, NY_T, 512, 256, 1,
       out + O_YS, 0, 512, nullptr, 0, 0, nullptr, 0, 0, bz, 1.0f, 0);
  // edge-rel scores
  hipLaunchKernelGGL(gsd_k, dim3(64), dim3(256), 0, stream, ybuf, Wg, G1, G2);
  hipLaunchKernelGGL(erel_k, dim3(1792), dim3(256), 0, stream, G1, G2, ei, bg, out + O_REL);
  hipLaunchKernelGGL(icopy_k, dim3(768), dim3(256), 0, stream, ei, et, out + O_EI, out + O_ET);
}